// Round 1
// baseline (742.015 us; speedup 1.0000x reference)
//
#include <hip/hip_runtime.h>
#include <math.h>

#define VOCAB 32000
#define EMB   32
#define HID   16
#define SEQ   128
#define BATCH 32
#define ROWS  (SEQ*BATCH)    // 4096
#define WIH_LD (EMB+HID)     // 48
#define VBLK  2048           // vocab tile per block (padded vocab 32768 = 16 tiles)
#define NVB   16
#define KPT   8              // vocab entries per thread = VBLK/256
#define RCH   128            // rows per chunk
#define NRC   32             // 4096/128

// ---------------------------------------------------------------------------
// Kernel 1: X[row][j] = b_ih[j] + sum_e W_ih[j][e] * emb[token[row]][e]
// (the input-dependent 2/3 of the RNN cell, fully parallel over rows)
// ---------------------------------------------------------------------------
__global__ __launch_bounds__(256) void k_embed(const int* __restrict__ tok,
    const float* __restrict__ emb, const float* __restrict__ Wih,
    const float* __restrict__ bih, float* __restrict__ X)
{
    __shared__ float sW[HID][EMB];
    __shared__ float sb[HID];
    int t = threadIdx.x;
    for (int i = t; i < HID*EMB; i += 256)
        sW[i/EMB][i%EMB] = Wih[(i/EMB)*WIH_LD + (i%EMB)];
    if (t < HID) sb[t] = bih[t];
    __syncthreads();

    int row = blockIdx.x*256 + t;         // grid = 16 blocks covers 4096 rows
    int token = tok[row];
    float x[EMB];
    const float4* ep = (const float4*)(emb + (long)token*EMB);
    #pragma unroll
    for (int q = 0; q < EMB/4; ++q) {
        float4 v = ep[q];
        x[4*q+0]=v.x; x[4*q+1]=v.y; x[4*q+2]=v.z; x[4*q+3]=v.w;
    }
    #pragma unroll
    for (int j = 0; j < HID; ++j) {
        float acc = sb[j];
        #pragma unroll
        for (int e = 0; e < EMB; ++e) acc = fmaf(sW[j][e], x[e], acc);
        X[row*HID + j] = acc;
    }
}

// ---------------------------------------------------------------------------
// Kernel 2: the serial recurrence. One block, 512 threads = (batch, j).
// h_new = tanh(X[s] + W_h @ h). W_h (16x16) and h (32x16) live in LDS.
// ---------------------------------------------------------------------------
__global__ __launch_bounds__(512) void k_rnn(const float* __restrict__ X,
    const float* __restrict__ h0, const float* __restrict__ Wih,
    float* __restrict__ H)
{
    __shared__ float sWh[HID][HID];
    __shared__ float h[BATCH][HID];
    int t = threadIdx.x;
    if (t < HID*HID)
        sWh[t/HID][t%HID] = Wih[(t/HID)*WIH_LD + EMB + (t%HID)];
    h[t>>4][t&15] = h0[t];                // 512 == BATCH*HID
    __syncthreads();

    int b = t >> 4, j = t & 15;
    for (int s = 0; s < SEQ; ++s) {
        int row = s*BATCH + b;
        float acc = X[row*HID + j];       // contiguous 2 KB read across block
        #pragma unroll
        for (int k = 0; k < HID; ++k) acc = fmaf(sWh[j][k], h[b][k], acc);
        // tanh via exp; |acc| <= ~6.3 by construction, clamp for safety
        float e2 = __expf(fminf(2.f*acc, 30.f));
        float hn = (e2 - 1.f) / (e2 + 1.f);
        __syncthreads();                  // all reads of h done
        h[b][j] = hn;
        H[row*HID + j] = hn;              // contiguous 2 KB write
        __syncthreads();
    }
}

// ---------------------------------------------------------------------------
// Kernel 3: per-row sum of exp(logit) -- partial per (row, vocab-tile, wave).
// W_ho tile held in REGISTERS (8 vocab x 16 floats/thread), reused across
// 128 rows per block => W_ho global traffic ~64 MB total instead of 8.4 GB.
// No max-subtraction: |logit| <= ~4.5 so f32 sumexp is exact-safe.
// ---------------------------------------------------------------------------
__global__ __launch_bounds__(256, 2) void k_sumexp(const float* __restrict__ Who,
    const float* __restrict__ bho, const float* __restrict__ H,
    float* __restrict__ part)
{
    int t = threadIdx.x;
    int vblk = blockIdx.x;                // 0..15
    float w[KPT][HID]; float bb[KPT];
    #pragma unroll
    for (int k = 0; k < KPT; ++k) {
        int v = vblk*VBLK + t + 256*k;
        if (v < VOCAB) {
            const float4* wp = (const float4*)(Who + (long)v*HID);
            #pragma unroll
            for (int q = 0; q < 4; ++q) {
                float4 f = wp[q];
                w[k][4*q+0]=f.x; w[k][4*q+1]=f.y; w[k][4*q+2]=f.z; w[k][4*q+3]=f.w;
            }
            bb[k] = bho[v];
        } else {
            #pragma unroll
            for (int i = 0; i < HID; ++i) w[k][i] = 0.f;
            bb[k] = -1e30f;               // exp(-1e30) == 0, padded lanes vanish
        }
    }

    for (int r = 0; r < RCH; ++r) {
        int row = blockIdx.y*RCH + r;
        float h[HID];
        const float4* hp = (const float4*)(H + row*HID);   // wave-uniform, L1 broadcast
        #pragma unroll
        for (int q = 0; q < 4; ++q) {
            float4 f = hp[q];
            h[4*q+0]=f.x; h[4*q+1]=f.y; h[4*q+2]=f.z; h[4*q+3]=f.w;
        }
        float p = 0.f;
        #pragma unroll
        for (int k = 0; k < KPT; ++k) {
            float acc = bb[k];
            #pragma unroll
            for (int i = 0; i < HID; ++i) acc = fmaf(w[k][i], h[i], acc);
            p += __expf(acc);
        }
        #pragma unroll
        for (int off = 32; off > 0; off >>= 1) p += __shfl_xor(p, off, 64);
        if ((t & 63) == 0)
            part[row*64 + vblk*4 + (t>>6)] = p;   // 64 partials per row
    }
}

// ---------------------------------------------------------------------------
// Kernel 4: logl[row] = log(sum of 64 partials). One wave per row.
// ---------------------------------------------------------------------------
__global__ __launch_bounds__(256) void k_logl(const float* __restrict__ part,
    float* __restrict__ logl)
{
    int t = threadIdx.x;
    int row = blockIdx.x*4 + (t>>6);      // grid = 1024 blocks x 4 waves
    int lane = t & 63;
    float p = part[row*64 + lane];        // coalesced
    #pragma unroll
    for (int off = 32; off > 0; off >>= 1) p += __shfl_xor(p, off, 64);
    if (lane == 0) logl[row] = logf(p);
}

// ---------------------------------------------------------------------------
// Kernel 5: out[row][v] = (h . W_ho[v] + b_ho[v]) - logl[row].
// Same register tile; recomputing logits (27 us of FLOPs) beats re-reading
// 524 MB. Stores are coalesced (v = base + tid + 256k). Write-bound.
// ---------------------------------------------------------------------------
__global__ __launch_bounds__(256, 2) void k_write(const float* __restrict__ Who,
    const float* __restrict__ bho, const float* __restrict__ H,
    const float* __restrict__ logl, float* __restrict__ out)
{
    int t = threadIdx.x;
    int vblk = blockIdx.x;
    float w[KPT][HID]; float bb[KPT]; int vv[KPT];
    #pragma unroll
    for (int k = 0; k < KPT; ++k) {
        int v = vblk*VBLK + t + 256*k; vv[k] = v;
        if (v < VOCAB) {
            const float4* wp = (const float4*)(Who + (long)v*HID);
            #pragma unroll
            for (int q = 0; q < 4; ++q) {
                float4 f = wp[q];
                w[k][4*q+0]=f.x; w[k][4*q+1]=f.y; w[k][4*q+2]=f.z; w[k][4*q+3]=f.w;
            }
            bb[k] = bho[v];
        } else {
            #pragma unroll
            for (int i = 0; i < HID; ++i) w[k][i] = 0.f;
            bb[k] = 0.f;
        }
    }

    for (int r = 0; r < RCH; ++r) {
        int row = blockIdx.y*RCH + r;
        float h[HID];
        const float4* hp = (const float4*)(H + row*HID);
        #pragma unroll
        for (int q = 0; q < 4; ++q) {
            float4 f = hp[q];
            h[4*q+0]=f.x; h[4*q+1]=f.y; h[4*q+2]=f.z; h[4*q+3]=f.w;
        }
        float ll = logl[row];
        float* orow = out + (long)row*VOCAB;
        #pragma unroll
        for (int k = 0; k < KPT; ++k) {
            if (vv[k] < VOCAB) {
                float acc = bb[k];
                #pragma unroll
                for (int i = 0; i < HID; ++i) acc = fmaf(w[k][i], h[i], acc);
                orow[vv[k]] = acc - ll;
            }
        }
    }
}

// ---------------------------------------------------------------------------
extern "C" void kernel_launch(void* const* d_in, const int* in_sizes, int n_in,
                              void* d_out, int out_size, void* d_ws, size_t ws_size,
                              hipStream_t stream)
{
    const int*   tok = (const int*)  d_in[0];  // (SEQ, BATCH)
    const float* h0  = (const float*)d_in[1];  // (BATCH, HID)
    const float* emb = (const float*)d_in[2];  // (VOCAB, EMB)
    const float* Wih = (const float*)d_in[3];  // (HID, EMB+HID)
    const float* bih = (const float*)d_in[4];  // (HID,)
    const float* Who = (const float*)d_in[5];  // (VOCAB, HID)
    const float* bho = (const float*)d_in[6];  // (VOCAB,)
    float* out = (float*)d_out;                // (SEQ, BATCH, VOCAB)

    char* ws = (char*)d_ws;
    float* X    = (float*)(ws);                // 4096*16*4 = 256 KB
    float* H    = (float*)(ws + 262144);       // 256 KB
    float* part = (float*)(ws + 524288);       // 4096*64*4 = 1 MB
    float* logl = (float*)(ws + 1572864);      // 16 KB

    k_embed <<<dim3(ROWS/256), 256, 0, stream>>>(tok, emb, Wih, bih, X);
    k_rnn   <<<dim3(1), 512, 0, stream>>>(X, h0, Wih, H);
    k_sumexp<<<dim3(NVB, NRC), 256, 0, stream>>>(Who, bho, H, part);
    k_logl  <<<dim3(ROWS/4), 256, 0, stream>>>(part, logl);
    k_write <<<dim3(NVB, NRC), 256, 0, stream>>>(Who, bho, H, logl, out);
}

// Round 2
// 713.002 us; speedup vs baseline: 1.0407x; 1.0407x over previous
//
#include <hip/hip_runtime.h>
#include <math.h>

#define VOCAB 32000
#define EMB   32
#define HID   16
#define SEQ   128
#define BATCH 32
#define ROWS  (SEQ*BATCH)    // 4096
#define WIH_LD (EMB+HID)     // 48
#define VBLK  2048           // vocab tile per block (padded vocab 32768 = 16 tiles)
#define NVB   16
#define RCH   128            // rows per block (y-dim chunk)
#define NRC   32             // 4096/128

// ---------------------------------------------------------------------------
// Kernel 1: X[row][j] = b_ih[j] + sum_e W_ih[j][e] * emb[token[row]][e]
// ---------------------------------------------------------------------------
__global__ __launch_bounds__(128) void k_embed(const int* __restrict__ tok,
    const float* __restrict__ emb, const float* __restrict__ Wih,
    const float* __restrict__ bih, float* __restrict__ X)
{
    __shared__ float sW[HID][EMB];
    __shared__ float sb[HID];
    int t = threadIdx.x;
    for (int i = t; i < HID*EMB; i += 128)
        sW[i/EMB][i%EMB] = Wih[(i/EMB)*WIH_LD + (i%EMB)];
    if (t < HID) sb[t] = bih[t];
    __syncthreads();

    int row = blockIdx.x*128 + t;         // 32 blocks x 128 = 4096 rows
    int token = tok[row];
    float x[EMB];
    const float4* ep = (const float4*)(emb + (long)token*EMB);
    #pragma unroll
    for (int q = 0; q < EMB/4; ++q) {
        float4 v = ep[q];
        x[4*q+0]=v.x; x[4*q+1]=v.y; x[4*q+2]=v.z; x[4*q+3]=v.w;
    }
    #pragma unroll
    for (int j = 0; j < HID; ++j) {
        float acc = sb[j];
        #pragma unroll
        for (int e = 0; e < EMB; ++e) acc = fmaf(sW[j][e], x[e], acc);
        X[row*HID + j] = acc;
    }
}

// ---------------------------------------------------------------------------
// Kernel 2: serial recurrence. One block, 512 threads = (batch, j).
// Double-buffered h in LDS -> ONE barrier per step; X row prefetched one
// step ahead so the global load latency overlaps the previous step's chain.
// ---------------------------------------------------------------------------
__global__ __launch_bounds__(512) void k_rnn(const float* __restrict__ X,
    const float* __restrict__ h0, const float* __restrict__ Wih,
    float* __restrict__ H)
{
    __shared__ float sWh[HID][HID];
    __shared__ float h[2][BATCH][HID];
    int t = threadIdx.x;
    if (t < HID*HID)
        sWh[t/HID][t%HID] = Wih[(t/HID)*WIH_LD + EMB + (t%HID)];
    h[0][t>>4][t&15] = h0[t];             // 512 == BATCH*HID
    __syncthreads();

    int b = t >> 4, j = t & 15;
    int cur = 0;
    float x = X[t];                        // step 0 row, coalesced
    for (int s = 0; s < SEQ; ++s) {
        float xn = (s+1 < SEQ) ? X[(s+1)*512 + t] : 0.f;   // prefetch (independent)
        float acc = x;
        #pragma unroll
        for (int k = 0; k < HID; ++k) acc = fmaf(sWh[j][k], h[cur][b][k], acc);
        float e2 = __expf(fminf(2.f*acc, 30.f));
        float hn = (e2 - 1.f) / (e2 + 1.f);
        h[cur^1][b][j] = hn;               // nobody reads buf cur^1 this step
        H[s*512 + t] = hn;                 // contiguous 2 KB write
        __syncthreads();                   // publish h[cur^1], retire reads of h[cur]
        x = xn; cur ^= 1;
    }
}

// ---------------------------------------------------------------------------
// Kernel 3: per-row sumexp partials. Each thread owns 8 vocab rows as two
// groups of 4 CONSECUTIVE rows (g in {0,1}) -> W_ho tile in registers
// (128 f32), reused across 128 rows. NR=2 rows per iteration so the two
// 6-deep shuffle-reduce chains interleave (ILP). No max-subtraction:
// |logit| <= ~4.5 so f32 sumexp is exact-safe.
// ---------------------------------------------------------------------------
__global__ __launch_bounds__(256, 2) void k_sumexp(const float* __restrict__ Who,
    const float* __restrict__ bho, const float* __restrict__ H,
    float* __restrict__ part)
{
    int t = threadIdx.x;
    int vblk = blockIdx.x;                 // 0..15
    float w[2][4][HID]; float bb[2][4];
    #pragma unroll
    for (int g = 0; g < 2; ++g) {
        int base = vblk*VBLK + g*1024 + 4*t;      // 4 consecutive vocab rows
        #pragma unroll
        for (int c = 0; c < 4; ++c) {
            int v = base + c;
            if (v < VOCAB) {
                const float4* wp = (const float4*)(Who + (long)v*HID);
                #pragma unroll
                for (int q = 0; q < 4; ++q) {
                    float4 f = wp[q];
                    w[g][c][4*q+0]=f.x; w[g][c][4*q+1]=f.y;
                    w[g][c][4*q+2]=f.z; w[g][c][4*q+3]=f.w;
                }
                bb[g][c] = bho[v];
            } else {
                #pragma unroll
                for (int i = 0; i < HID; ++i) w[g][c][i] = 0.f;
                bb[g][c] = -1e30f;         // exp -> 0 for padded lanes
            }
        }
    }

    int wid = t >> 6, lane = t & 63;
    for (int r = 0; r < RCH; r += 2) {
        int row0 = blockIdx.y*RCH + r;
        float h0[HID], h1[HID];
        const float4* hp0 = (const float4*)(H + row0*HID);      // uniform -> s_load
        const float4* hp1 = (const float4*)(H + (row0+1)*HID);
        #pragma unroll
        for (int q = 0; q < 4; ++q) {
            float4 f0 = hp0[q], f1 = hp1[q];
            h0[4*q+0]=f0.x; h0[4*q+1]=f0.y; h0[4*q+2]=f0.z; h0[4*q+3]=f0.w;
            h1[4*q+0]=f1.x; h1[4*q+1]=f1.y; h1[4*q+2]=f1.z; h1[4*q+3]=f1.w;
        }
        float p0 = 0.f, p1 = 0.f;
        #pragma unroll
        for (int g = 0; g < 2; ++g)
        #pragma unroll
        for (int c = 0; c < 4; ++c) {
            float a0 = bb[g][c], a1 = bb[g][c];
            #pragma unroll
            for (int i = 0; i < HID; ++i) {
                a0 = fmaf(w[g][c][i], h0[i], a0);
                a1 = fmaf(w[g][c][i], h1[i], a1);
            }
            p0 += __expf(a0);
            p1 += __expf(a1);
        }
        #pragma unroll
        for (int off = 32; off > 0; off >>= 1) {   // two independent chains
            p0 += __shfl_xor(p0, off, 64);
            p1 += __shfl_xor(p1, off, 64);
        }
        if (lane == 0) {
            part[(long)row0*64     + vblk*4 + wid] = p0;
            part[(long)(row0+1)*64 + vblk*4 + wid] = p1;
        }
    }
}

// ---------------------------------------------------------------------------
// Kernel 4: logl[row] = log(sum of 64 partials). One wave per row.
// ---------------------------------------------------------------------------
__global__ __launch_bounds__(256) void k_logl(const float* __restrict__ part,
    float* __restrict__ logl)
{
    int t = threadIdx.x;
    int row = blockIdx.x*4 + (t>>6);
    int lane = t & 63;
    float p = part[row*64 + lane];
    #pragma unroll
    for (int off = 32; off > 0; off >>= 1) p += __shfl_xor(p, off, 64);
    if (lane == 0) logl[row] = logf(p);
}

// ---------------------------------------------------------------------------
// Kernel 5: out[row][v] = logit - logl[row], recomputed with the same
// register tile; stores are global_store_dwordx4 (4 consecutive vocab per
// thread). Write-bound: floor = 524 MB / 6.3 TB/s ~= 85 us.
// ---------------------------------------------------------------------------
__global__ __launch_bounds__(256, 2) void k_write(const float* __restrict__ Who,
    const float* __restrict__ bho, const float* __restrict__ H,
    const float* __restrict__ logl, float* __restrict__ out)
{
    int t = threadIdx.x;
    int vblk = blockIdx.x;
    float w[2][4][HID]; float bb[2][4];
    #pragma unroll
    for (int g = 0; g < 2; ++g) {
        int base = vblk*VBLK + g*1024 + 4*t;
        #pragma unroll
        for (int c = 0; c < 4; ++c) {
            int v = base + c;
            if (v < VOCAB) {
                const float4* wp = (const float4*)(Who + (long)v*HID);
                #pragma unroll
                for (int q = 0; q < 4; ++q) {
                    float4 f = wp[q];
                    w[g][c][4*q+0]=f.x; w[g][c][4*q+1]=f.y;
                    w[g][c][4*q+2]=f.z; w[g][c][4*q+3]=f.w;
                }
                bb[g][c] = bho[v];
            } else {
                #pragma unroll
                for (int i = 0; i < HID; ++i) w[g][c][i] = 0.f;
                bb[g][c] = 0.f;
            }
        }
    }

    for (int r = 0; r < RCH; ++r) {
        int row = blockIdx.y*RCH + r;
        float h[HID];
        const float4* hp = (const float4*)(H + row*HID);
        #pragma unroll
        for (int q = 0; q < 4; ++q) {
            float4 f = hp[q];
            h[4*q+0]=f.x; h[4*q+1]=f.y; h[4*q+2]=f.z; h[4*q+3]=f.w;
        }
        float ll = logl[row];
        float* orow = out + (long)row*VOCAB;
        #pragma unroll
        for (int g = 0; g < 2; ++g) {
            int base = vblk*VBLK + g*1024 + 4*t;
            float acc[4];
            #pragma unroll
            for (int c = 0; c < 4; ++c) {
                float a = bb[g][c];
                #pragma unroll
                for (int i = 0; i < HID; ++i) a = fmaf(w[g][c][i], h[i], a);
                acc[c] = a - ll;
            }
            if (base < VOCAB) {            // VOCAB%4==0 -> whole float4 valid
                float4 o; o.x=acc[0]; o.y=acc[1]; o.z=acc[2]; o.w=acc[3];
                *(float4*)(orow + base) = o;
            }
        }
    }
}

// ---------------------------------------------------------------------------
extern "C" void kernel_launch(void* const* d_in, const int* in_sizes, int n_in,
                              void* d_out, int out_size, void* d_ws, size_t ws_size,
                              hipStream_t stream)
{
    const int*   tok = (const int*)  d_in[0];  // (SEQ, BATCH)
    const float* h0  = (const float*)d_in[1];  // (BATCH, HID)
    const float* emb = (const float*)d_in[2];  // (VOCAB, EMB)
    const float* Wih = (const float*)d_in[3];  // (HID, EMB+HID)
    const float* bih = (const float*)d_in[4];  // (HID,)
    const float* Who = (const float*)d_in[5];  // (VOCAB, HID)
    const float* bho = (const float*)d_in[6];  // (VOCAB,)
    float* out = (float*)d_out;                // (SEQ, BATCH, VOCAB)

    char* ws = (char*)d_ws;
    float* X    = (float*)(ws);                // 256 KB
    float* H    = (float*)(ws + 262144);       // 256 KB
    float* part = (float*)(ws + 524288);       // 1 MB
    float* logl = (float*)(ws + 1572864);      // 16 KB

    k_embed <<<dim3(ROWS/128), 128, 0, stream>>>(tok, emb, Wih, bih, X);
    k_rnn   <<<dim3(1), 512, 0, stream>>>(X, h0, Wih, H);
    k_sumexp<<<dim3(NVB, NRC), 256, 0, stream>>>(Who, bho, H, part);
    k_logl  <<<dim3(ROWS/4), 256, 0, stream>>>(part, logl);
    k_write <<<dim3(NVB, NRC), 256, 0, stream>>>(Who, bho, H, logl, out);
}